// Round 6
// baseline (205.371 us; speedup 1.0000x reference)
//
#include <hip/hip_runtime.h>
#include <hip/hip_fp16.h>

#define N_NODES 50000
#define N_EDGES 1600000
#define IN_DIM 256
#define OUT_DIM 128
#define NEG_SLOPE 0.01f

// ---- two-level scatter geometry ----
#define SB_SH     10
#define SB_ROWS   1024                                  // rows per super-bin
#define NSB       ((N_NODES + SB_ROWS - 1) / SB_ROWS)   // 49
#define SB_CAP    34816                                 // mean ~32.7K, sd ~181 -> +11 sigma
#define PASSB_SPLIT 8                                   // blocks per super-bin in pass B
#define PB_ITERS  ((SB_CAP / PASSB_SPLIT + 511) / 512)  // 9

#define BIN_SH    5
#define BIN_ROWS  32                                    // rows per fine bin
#define NBIN      ((N_NODES + BIN_ROWS - 1) / BIN_ROWS) // 1563
#define NBIN_PAD  (NSB * (SB_ROWS / BIN_ROWS))          // 1568 (cursor array)
#define CAPB      1280                                  // mean 1023, sd 32 -> +8 sigma
#define OVF_CAP   65536                                 // spill net (never used in practice)

#define SCAT_BLOCKS 256
#define CONVW_BLOCKS 8                   // extra blocks: W fp32 -> f16 frag layout
#define EPB_S (N_EDGES / SCAT_BLOCKS)    // 6250
#define SCAT_ITERS ((EPB_S + 511) / 512) // 13

typedef _Float16 f16x8 __attribute__((ext_vector_type(8)));
typedef float    f32x4 __attribute__((ext_vector_type(4)));
typedef float    f32x8 __attribute__((ext_vector_type(8)));

__device__ __forceinline__ float lrelu(float v) {
    return v >= 0.f ? v : NEG_SLOPE * v;
}

// ---------------------------------------------------------------------------
// Kernel 1: h = x @ W via v_mfma_f32_16x16x32_f16 (f16 inputs, fp32 accum).
// ~29 us, memory-bound on 51 MB x-read. Unchanged.
// ---------------------------------------------------------------------------
#define BM 128
#define GEMM_BLOCKS ((N_NODES + BM - 1) / BM)   // 391

#define CVT16(lo, hi) do { \
    lo[0]=(_Float16)xr[0].x; lo[1]=(_Float16)xr[0].y; lo[2]=(_Float16)xr[0].z; lo[3]=(_Float16)xr[0].w; \
    lo[4]=(_Float16)xr[1].x; lo[5]=(_Float16)xr[1].y; lo[6]=(_Float16)xr[1].z; lo[7]=(_Float16)xr[1].w; \
    hi[0]=(_Float16)xr[2].x; hi[1]=(_Float16)xr[2].y; hi[2]=(_Float16)xr[2].z; hi[3]=(_Float16)xr[2].w; \
    hi[4]=(_Float16)xr[3].x; hi[5]=(_Float16)xr[3].y; hi[6]=(_Float16)xr[3].z; hi[7]=(_Float16)xr[3].w; \
} while (0)

__global__ __launch_bounds__(256, 2) void gemm_xw_mfma(const float* __restrict__ x,
                                                       const __half* __restrict__ wtl,
                                                       __half* __restrict__ h) {
    __shared__ f16x8 wt8[32 * 128];   // [kgi=k/8][n] -> 8 halves k..k+7 : 64 KB
    __shared__ f16x8 xs8[2][4][BM];   // [buf][kg][m] -> 8 halves         : 16 KB

    const int t    = threadIdx.x;
    const int lane = t & 63;
    const int wv   = t >> 6;
    const int row0 = blockIdx.x * BM;

    {
        const int4* src = (const int4*)wtl;
        int4* dst = (int4*)wt8;
#pragma unroll
        for (int i = 0; i < 16; ++i) dst[i * 256 + t] = src[i * 256 + t];
    }

    const int srow = t >> 1;
    const int skh  = t & 1;
    const int grow = row0 + srow;
    const bool rv  = grow < N_NODES;
    const float* xp = x + (size_t)(rv ? grow : 0) * IN_DIM + skh * 16;

    float4 xr[4];
#pragma unroll
    for (int i = 0; i < 4; ++i)
        xr[i] = rv ? ((const float4*)xp)[i] : make_float4(0.f, 0.f, 0.f, 0.f);
    {
        f16x8 lo, hi;
        CVT16(lo, hi);
        xs8[0][skh * 2 + 0][srow] = lo;
        xs8[0][skh * 2 + 1][srow] = hi;
    }
    __syncthreads();

    f32x4 acc[2][8];
#pragma unroll
    for (int mf = 0; mf < 2; ++mf)
#pragma unroll
        for (int nf = 0; nf < 8; ++nf) acc[mf][nf] = (f32x4){0.f, 0.f, 0.f, 0.f};

    const int kg  = lane >> 4;
    const int l15 = lane & 15;
    const int mb  = (wv << 5) + l15;

#pragma unroll
    for (int ks = 0; ks < 8; ++ks) {
        const int cur = ks & 1;
        if (ks < 7) {
#pragma unroll
            for (int i = 0; i < 4; ++i)
                xr[i] = rv ? ((const float4*)(xp + (ks + 1) * 32))[i]
                           : make_float4(0.f, 0.f, 0.f, 0.f);
        }
        const f16x8 b0 = xs8[cur][kg][mb];
        const f16x8 b1 = xs8[cur][kg][mb + 16];
#pragma unroll
        for (int nf = 0; nf < 8; ++nf) {
            const f16x8 a = wt8[(((ks << 2) | kg) << 7) + (nf << 4) + l15];
            acc[0][nf] = __builtin_amdgcn_mfma_f32_16x16x32_f16(a, b0, acc[0][nf], 0, 0, 0);
            acc[1][nf] = __builtin_amdgcn_mfma_f32_16x16x32_f16(a, b1, acc[1][nf], 0, 0, 0);
        }
        if (ks < 7) {
            f16x8 lo, hi;
            CVT16(lo, hi);
            xs8[cur ^ 1][skh * 2 + 0][srow] = lo;
            xs8[cur ^ 1][skh * 2 + 1][srow] = hi;
            __syncthreads();
        }
    }

    const int rg = lane >> 4;
#pragma unroll
    for (int mf = 0; mf < 2; ++mf) {
        const int m = row0 + (wv << 5) + (mf << 4) + l15;
        if (m < N_NODES) {
            __half* hp = h + (size_t)m * OUT_DIM + (rg << 2);
#pragma unroll
            for (int nf = 0; nf < 8; ++nf) {
                union { ushort4 u; __half f[4]; } o;
                o.f[0] = __float2half(acc[mf][nf][0]);
                o.f[1] = __float2half(acc[mf][nf][1]);
                o.f[2] = __float2half(acc[mf][nf][2]);
                o.f[3] = __float2half(acc[mf][nf][3]);
                *(ushort4*)(hp + (nf << 4)) = o.u;
            }
        }
    }
}

// ---------------------------------------------------------------------------
// Kernel 2 (pass A, coarse scatter): bin edges into 49 super-bins of 1024
// rows. Per (block, sbin) run ~128 records = 1 KB -> near-perfect write-line
// utilization. Record: { row<<16 | col , val_bits }. Spill -> side buffer.
// Blocks >= SCAT_BLOCKS transform W fp32 -> f16 frag layout (precedes gemm).
// ---------------------------------------------------------------------------
__global__ __launch_bounds__(512) void scatter_coarse(const int* __restrict__ rows,
                                                      const int* __restrict__ cols,
                                                      const float* __restrict__ vals,
                                                      int* __restrict__ sbcur,
                                                      int* __restrict__ ovfcnt,
                                                      int2* __restrict__ cbuf,
                                                      int2* __restrict__ ovfbuf,
                                                      const float* __restrict__ w,
                                                      __half* __restrict__ wtl) {
    if (blockIdx.x >= SCAT_BLOCKS) {
        const int e0 = ((blockIdx.x - SCAT_BLOCKS) * 512 + threadIdx.x) * 8;
        const int k  = e0 >> 7;
        const int n0 = e0 & 127;
        const float4 a = *(const float4*)(w + e0);
        const float4 b = *(const float4*)(w + e0 + 4);
        __half* dst = wtl + ((size_t)((k >> 3) * 128 + n0)) * 8 + (k & 7);
        dst[0]  = __float2half(a.x);
        dst[8]  = __float2half(a.y);
        dst[16] = __float2half(a.z);
        dst[24] = __float2half(a.w);
        dst[32] = __float2half(b.x);
        dst[40] = __float2half(b.y);
        dst[48] = __float2half(b.z);
        dst[56] = __float2half(b.w);
        return;
    }

    __shared__ int lcur[NSB];
    const int t = threadIdx.x;
    const int ebase = blockIdx.x * EPB_S;

    if (t < NSB) lcur[t] = 0;
    __syncthreads();

    int myr[SCAT_ITERS];
#pragma unroll
    for (int k = 0; k < SCAT_ITERS; ++k) {
        const int i = k * 512 + t;
        myr[k] = -1;
        if (i < EPB_S) {
            const int r = rows[ebase + i];
            myr[k] = r;
            atomicAdd(&lcur[r >> SB_SH], 1);
        }
    }
    __syncthreads();

    if (t < NSB) {
        const int c = lcur[t];
        lcur[t] = (c > 0) ? atomicAdd(&sbcur[t], c) : 0;
    }
    __syncthreads();

#pragma unroll
    for (int k = 0; k < SCAT_ITERS; ++k) {
        const int i = k * 512 + t;
        if (i < EPB_S) {
            const int e = ebase + i;
            const int r = myr[k];
            const int sb = r >> SB_SH;
            const int off = atomicAdd(&lcur[sb], 1);
            const int key = (int)(((unsigned)r << 16) | (unsigned)cols[e]);
            const int vb  = __float_as_int(vals[e]);
            if (off < SB_CAP) {
                cbuf[(size_t)sb * SB_CAP + off] = make_int2(key, vb);
            } else {
                const int p = atomicAdd(ovfcnt, 1);
                if (p < OVF_CAP) ovfbuf[p] = make_int2(key, vb);
            }
        }
    }
}

// ---------------------------------------------------------------------------
// Kernel 3 (pass B, fine scatter): 8 blocks per super-bin re-scatter its
// (L2-hot) records into the 32 fine bins it covers. Coalesced runs ~136.
// Fine record: { col | (row & 31) << 16 , val_bits }.
// ---------------------------------------------------------------------------
__global__ __launch_bounds__(512) void scatter_fine(const int* __restrict__ sbcur,
                                                    int* __restrict__ fcur,
                                                    int* __restrict__ ovfcnt,
                                                    const int2* __restrict__ cbuf,
                                                    int2* __restrict__ ebuf,
                                                    int2* __restrict__ ovfbuf) {
    __shared__ int lcur[SB_ROWS / BIN_ROWS];   // 32
    const int t    = threadIdx.x;
    const int sb   = blockIdx.x / PASSB_SPLIT;
    const int part = blockIdx.x % PASSB_SPLIT;

    const int cnt_sb = min(sbcur[sb], SB_CAP);
    const int chunk  = (cnt_sb + PASSB_SPLIT - 1) / PASSB_SPLIT;
    const int i0 = part * chunk;
    const int i1 = min(i0 + chunk, cnt_sb);

    if (t < 32) lcur[t] = 0;
    __syncthreads();

    int2 rc[PB_ITERS];
#pragma unroll
    for (int k = 0; k < PB_ITERS; ++k) {
        const int i = i0 + k * 512 + t;
        if (i < i1) {
            rc[k] = cbuf[(size_t)sb * SB_CAP + i];
            const unsigned urow = ((unsigned)rc[k].x) >> 16;
            atomicAdd(&lcur[(urow >> BIN_SH) & 31], 1);
        }
    }
    __syncthreads();

    if (t < 32) {
        const int c = lcur[t];
        lcur[t] = (c > 0) ? atomicAdd(&fcur[(sb << 5) + t], c) : 0;
    }
    __syncthreads();

#pragma unroll
    for (int k = 0; k < PB_ITERS; ++k) {
        const int i = i0 + k * 512 + t;
        if (i < i1) {
            const unsigned urow = ((unsigned)rc[k].x) >> 16;
            const int f   = (int)(urow >> BIN_SH);
            const int off = atomicAdd(&lcur[(urow >> BIN_SH) & 31], 1);
            const int key = (rc[k].x & 0xFFFF) | (int)((urow & (BIN_ROWS - 1)) << 16);
            if (off < CAPB) {
                ebuf[(size_t)f * CAPB + off] = make_int2(key, rc[k].y);
            } else {
                const int p = atomicAdd(ovfcnt, 1);
                if (p < OVF_CAP) ovfbuf[p] = rc[k];   // full-row format
            }
        }
    }
}

// ---------------------------------------------------------------------------
// Kernel 4 (FUSED sort+gather, MLP-pipelined). One block per 32-row bin.
// Pass 1 stages raw records in LDS + 256-class (row,octant) histogram.
// Cheap 4-wave shfl scan. Pass 2 sorts LDS->LDS. Gather: each wave owns 4
// rows (4 independent f32x8 accumulators); software pipeline depth 2 ->
// 8 h-loads in flight per wave (vs 2 before) to break the load->FMA
// latency serialization that pinned rounds 1-5 at ~57 us.
// ---------------------------------------------------------------------------
#define NCLS 256

#define STAGE(IT, HV, VV) do {                                                  \
    _Pragma("unroll")                                                           \
    for (int q = 0; q < 4; ++q) {                                               \
        const int idx = beg[q] + ((IT) << 2) + grp;                             \
        const bool vld = idx < end[q];                                          \
        const int2 r = srec[vld ? idx : 0];                                     \
        VV[q] = vld ? __int_as_float(r.y) : 0.f;                                \
        HV[q] = *(const f16x8*)(h + (size_t)(r.x & 0xFFFF) * OUT_DIM + (gl << 3)); \
    }                                                                           \
} while (0)

__global__ __launch_bounds__(512, 4) void sort_gather(const int* __restrict__ fcur,
                                                      const int* __restrict__ ovfcnt,
                                                      const int2* __restrict__ ebuf,
                                                      const int2* __restrict__ ovfbuf,
                                                      const __half* __restrict__ h,
                                                      float* __restrict__ out) {
    __shared__ int2 urec[CAPB];            // 10 KB raw staged records
    __shared__ int2 srec[CAPB];            // 10 KB sorted records
    __shared__ int  hist[NCLS];
    __shared__ int  pfx[NCLS];
    __shared__ int  rowoff_l[BIN_ROWS + 1];
    __shared__ int  wsum[4];

    const int t    = threadIdx.x;
    const int bin  = blockIdx.x;
    const int wv   = t >> 6;
    const int lane = t & 63;

    const int cnt_all = fcur[bin];
    const int cnt     = cnt_all < CAPB ? cnt_all : CAPB;
    const size_t base = (size_t)bin * CAPB;

    if (t < NCLS) hist[t] = 0;
    __syncthreads();

    // ---- pass 1: stage to LDS + per-(row,octant) histogram ----
    for (int i = t; i < cnt; i += 512) {
        const int2 r = ebuf[base + i];
        urec[i] = r;
        atomicAdd(&hist[(((r.x >> 16) & 31) << 3) | ((r.x & 0xFFFF) >> 13)], 1);
    }
    __syncthreads();

    // ---- 256-class scan: 4-wave shfl scan + tiny combine ----
    {
        const int v = (t < NCLS) ? hist[t] : 0;
        int s = v;
#pragma unroll
        for (int off = 1; off < 64; off <<= 1) {
            const int u = __shfl_up(s, off);
            if (lane >= off) s += u;
        }
        if (t < NCLS && lane == 63) wsum[wv] = s;
        __syncthreads();
        if (t == 0) {
            int a = 0;
#pragma unroll
            for (int i = 0; i < 4; ++i) { const int c = wsum[i]; wsum[i] = a; a += c; }
        }
        __syncthreads();
        if (t < NCLS) {
            const int incl = s + wsum[wv];
            pfx[t]  = incl;
            hist[t] = incl - v;            // exclusive -> sort cursor
        }
    }
    __syncthreads();
    if (t < BIN_ROWS) rowoff_l[t] = t ? pfx[(t << 3) - 1] : 0;
    if (t == BIN_ROWS) rowoff_l[BIN_ROWS] = cnt;
    __syncthreads();

    // ---- pass 2: counting sort LDS -> LDS ----
    for (int i = t; i < cnt; i += 512) {
        const int2 r = urec[i];
        const int cls = (((r.x >> 16) & 31) << 3) | ((r.x & 0xFFFF) >> 13);
        const int pos = atomicAdd(&hist[cls], 1);
        srec[pos] = r;
    }
    __syncthreads();

    // ---- gather: wave owns 4 rows, depth-2 pipeline, 8 loads in flight ----
    const int grp = lane >> 4;             // edge slot within 4-edge group
    const int gl  = lane & 15;             // 16 lanes span one 256 B h row
    const int r0  = wv << 2;               // this wave's rows r0..r0+3

    int beg[4], end[4];
#pragma unroll
    for (int q = 0; q < 4; ++q) { beg[q] = rowoff_l[r0 + q]; end[q] = rowoff_l[r0 + q + 1]; }
    int nmax = 0;
#pragma unroll
    for (int q = 0; q < 4; ++q) nmax = max(nmax, end[q] - beg[q]);
    const int iters = (nmax + 3) >> 2;

    f32x8 acc[4];
#pragma unroll
    for (int q = 0; q < 4; ++q) acc[q] = (f32x8){0.f,0.f,0.f,0.f,0.f,0.f,0.f,0.f};

    f16x8 hc[4], hn[4];
    float vc[4], vn[4];
    if (iters > 0) STAGE(0, hc, vc);
    for (int it = 0; it < iters; ++it) {
        if (it + 1 < iters) STAGE(it + 1, hn, vn);
#pragma unroll
        for (int q = 0; q < 4; ++q)
#pragma unroll
            for (int j = 0; j < 8; ++j) acc[q][j] += vc[q] * (float)hc[q][j];
#pragma unroll
        for (int q = 0; q < 4; ++q) { hc[q] = hn[q]; vc[q] = vn[q]; }
    }

    // ---- overflow replay (0 in practice; grp 0 adds once) ----
    int novf = *ovfcnt;
    if (novf > OVF_CAP) novf = OVF_CAP;
    for (int e = 0; e < novf; ++e) {
        const int2 rec = ovfbuf[e];
        const unsigned urow = ((unsigned)rec.x) >> 16;
        if ((int)(urow >> BIN_SH) == bin && grp == 0) {
            const int lr = (int)(urow & (BIN_ROWS - 1)) - r0;
            if (lr >= 0 && lr < 4) {
                const float v = __int_as_float(rec.y);
                const f16x8 hv = *(const f16x8*)(h + (size_t)(rec.x & 0xFFFF) * OUT_DIM + (gl << 3));
#pragma unroll
                for (int q = 0; q < 4; ++q)
                    if (q == lr)
#pragma unroll
                        for (int j = 0; j < 8; ++j) acc[q][j] += v * (float)hv[j];
            }
        }
    }

    // ---- reduce across the 4 edge-slot groups ----
#pragma unroll
    for (int q = 0; q < 4; ++q)
#pragma unroll
        for (int j = 0; j < 8; ++j) {
            float x = acc[q][j];
            x += __shfl_xor(x, 16);
            x += __shfl_xor(x, 32);
            acc[q][j] = x;
        }

    // ---- grp g stores row r0+g (static-index select), fused leaky-ReLU ----
    float res[8];
#pragma unroll
    for (int j = 0; j < 8; ++j) {
        float x = acc[0][j];
        x = (grp == 1) ? acc[1][j] : x;
        x = (grp == 2) ? acc[2][j] : x;
        x = (grp == 3) ? acc[3][j] : x;
        res[j] = lrelu(x);
    }
    const int grow = (bin << BIN_SH) + r0 + grp;
    if (grow < N_NODES) {
        float* op = out + (size_t)grow * OUT_DIM + (gl << 3);
        *(float4*)op       = make_float4(res[0], res[1], res[2], res[3]);
        *(float4*)(op + 4) = make_float4(res[4], res[5], res[6], res[7]);
    }
}

// ---------------------------------------------------------------------------
// Launch: memset -> coarse scatter(+W-convert) -> fine scatter -> gemm ->
// sort_gather. cbuf is dead before gemm runs, so h ALIASES it.
// ---------------------------------------------------------------------------
extern "C" void kernel_launch(void* const* d_in, const int* in_sizes, int n_in,
                              void* d_out, int out_size, void* d_ws, size_t ws_size,
                              hipStream_t stream) {
    const float* x    = (const float*)d_in[0];
    const float* w    = (const float*)d_in[1];
    const float* vals = (const float*)d_in[2];
    const int*   rows = (const int*)d_in[3];
    const int*   cols = (const int*)d_in[4];
    float* out = (float*)d_out;

    char* ws = (char*)d_ws;
    size_t off = 0;
    auto alloc = [&](size_t bytes) {
        void* p = ws + off;
        off = (off + bytes + 255) & ~(size_t)255;
        return p;
    };
    int2*  cbuf    = (int2*) alloc((size_t)NSB * SB_CAP * sizeof(int2));           // 13.7 MB
    __half* h      = (__half*)cbuf;   // alias: h (12.8 MB) reuses dead cbuf
    int2*  ebuf    = (int2*) alloc((size_t)NBIN * CAPB * sizeof(int2));            // 16.0 MB
    int2*  ovfbuf  = (int2*) alloc((size_t)OVF_CAP * sizeof(int2));                // 0.5 MB
    __half* wtl    = (__half*)alloc((size_t)IN_DIM * OUT_DIM * sizeof(__half));    // 64 KB
    int*   meta    = (int*)  alloc((size_t)(NSB + NBIN_PAD + 1) * sizeof(int));
    int*   sbcur   = meta;
    int*   fcur    = meta + NSB;
    int*   ovfcnt  = meta + NSB + NBIN_PAD;

    hipMemsetAsync(meta, 0, (size_t)(NSB + NBIN_PAD + 1) * sizeof(int), stream);

    scatter_coarse<<<SCAT_BLOCKS + CONVW_BLOCKS, 512, 0, stream>>>(rows, cols, vals,
                                                                   sbcur, ovfcnt, cbuf, ovfbuf, w, wtl);
    scatter_fine<<<NSB * PASSB_SPLIT, 512, 0, stream>>>(sbcur, fcur, ovfcnt, cbuf, ebuf, ovfbuf);
    gemm_xw_mfma<<<GEMM_BLOCKS, 256, 0, stream>>>(x, wtl, h);
    sort_gather<<<NBIN, 512, 0, stream>>>(fcur, ovfcnt, ebuf, ovfbuf, h, out);
}

// Round 7
// 198.240 us; speedup vs baseline: 1.0360x; 1.0360x over previous
//
#include <hip/hip_runtime.h>
#include <hip/hip_fp16.h>

#define N_NODES 50000
#define N_EDGES 1600000
#define IN_DIM 256
#define OUT_DIM 128
#define NEG_SLOPE 0.01f

// ---- two-level scatter, deterministic slots (ZERO global atomics) ----
#define SB_SH     10
#define SB_ROWS   1024
#define NSB       ((N_NODES + SB_ROWS - 1) / SB_ROWS)   // 49
#define SEG       208                                   // records per segment (+7 sigma)

#define BIN_SH    5
#define BIN_ROWS  32
#define NBIN      ((N_NODES + BIN_ROWS - 1) / BIN_ROWS) // 1563
#define NBIN_PAD  (NSB * 32)                            // 1568
#define NPART     8                                     // fine parts per super-bin
#define CAPB_TOT  (NPART * SEG)                         // 1664 max records/bin
#define OVF_CAP   65536

#define SCAT_BLOCKS 256
#define CONVW_BLOCKS 8
#define EPB_S (N_EDGES / SCAT_BLOCKS)    // 6250
#define SCAT_ITERS ((EPB_S + 511) / 512) // 13

typedef _Float16 f16x8 __attribute__((ext_vector_type(8)));
typedef float    f32x4 __attribute__((ext_vector_type(4)));
typedef float    f32x8 __attribute__((ext_vector_type(8)));

__device__ __forceinline__ float lrelu(float v) {
    return v >= 0.f ? v : NEG_SLOPE * v;
}

// ---------------------------------------------------------------------------
// Kernel 1: h = x @ W via v_mfma_f32_16x16x32_f16. Unchanged.
// ---------------------------------------------------------------------------
#define BM 128
#define GEMM_BLOCKS ((N_NODES + BM - 1) / BM)   // 391

#define CVT16(lo, hi) do { \
    lo[0]=(_Float16)xr[0].x; lo[1]=(_Float16)xr[0].y; lo[2]=(_Float16)xr[0].z; lo[3]=(_Float16)xr[0].w; \
    lo[4]=(_Float16)xr[1].x; lo[5]=(_Float16)xr[1].y; lo[6]=(_Float16)xr[1].z; lo[7]=(_Float16)xr[1].w; \
    hi[0]=(_Float16)xr[2].x; hi[1]=(_Float16)xr[2].y; hi[2]=(_Float16)xr[2].z; hi[3]=(_Float16)xr[2].w; \
    hi[4]=(_Float16)xr[3].x; hi[5]=(_Float16)xr[3].y; hi[6]=(_Float16)xr[3].z; hi[7]=(_Float16)xr[3].w; \
} while (0)

__global__ __launch_bounds__(256, 2) void gemm_xw_mfma(const float* __restrict__ x,
                                                       const __half* __restrict__ wtl,
                                                       __half* __restrict__ h) {
    __shared__ f16x8 wt8[32 * 128];
    __shared__ f16x8 xs8[2][4][BM];

    const int t    = threadIdx.x;
    const int lane = t & 63;
    const int wv   = t >> 6;
    const int row0 = blockIdx.x * BM;

    {
        const int4* src = (const int4*)wtl;
        int4* dst = (int4*)wt8;
#pragma unroll
        for (int i = 0; i < 16; ++i) dst[i * 256 + t] = src[i * 256 + t];
    }

    const int srow = t >> 1;
    const int skh  = t & 1;
    const int grow = row0 + srow;
    const bool rv  = grow < N_NODES;
    const float* xp = x + (size_t)(rv ? grow : 0) * IN_DIM + skh * 16;

    float4 xr[4];
#pragma unroll
    for (int i = 0; i < 4; ++i)
        xr[i] = rv ? ((const float4*)xp)[i] : make_float4(0.f, 0.f, 0.f, 0.f);
    {
        f16x8 lo, hi;
        CVT16(lo, hi);
        xs8[0][skh * 2 + 0][srow] = lo;
        xs8[0][skh * 2 + 1][srow] = hi;
    }
    __syncthreads();

    f32x4 acc[2][8];
#pragma unroll
    for (int mf = 0; mf < 2; ++mf)
#pragma unroll
        for (int nf = 0; nf < 8; ++nf) acc[mf][nf] = (f32x4){0.f, 0.f, 0.f, 0.f};

    const int kg  = lane >> 4;
    const int l15 = lane & 15;
    const int mb  = (wv << 5) + l15;

#pragma unroll
    for (int ks = 0; ks < 8; ++ks) {
        const int cur = ks & 1;
        if (ks < 7) {
#pragma unroll
            for (int i = 0; i < 4; ++i)
                xr[i] = rv ? ((const float4*)(xp + (ks + 1) * 32))[i]
                           : make_float4(0.f, 0.f, 0.f, 0.f);
        }
        const f16x8 b0 = xs8[cur][kg][mb];
        const f16x8 b1 = xs8[cur][kg][mb + 16];
#pragma unroll
        for (int nf = 0; nf < 8; ++nf) {
            const f16x8 a = wt8[(((ks << 2) | kg) << 7) + (nf << 4) + l15];
            acc[0][nf] = __builtin_amdgcn_mfma_f32_16x16x32_f16(a, b0, acc[0][nf], 0, 0, 0);
            acc[1][nf] = __builtin_amdgcn_mfma_f32_16x16x32_f16(a, b1, acc[1][nf], 0, 0, 0);
        }
        if (ks < 7) {
            f16x8 lo, hi;
            CVT16(lo, hi);
            xs8[cur ^ 1][skh * 2 + 0][srow] = lo;
            xs8[cur ^ 1][skh * 2 + 1][srow] = hi;
            __syncthreads();
        }
    }

    const int rg = lane >> 4;
#pragma unroll
    for (int mf = 0; mf < 2; ++mf) {
        const int m = row0 + (wv << 5) + (mf << 4) + l15;
        if (m < N_NODES) {
            __half* hp = h + (size_t)m * OUT_DIM + (rg << 2);
#pragma unroll
            for (int nf = 0; nf < 8; ++nf) {
                union { ushort4 u; __half f[4]; } o;
                o.f[0] = __float2half(acc[mf][nf][0]);
                o.f[1] = __float2half(acc[mf][nf][1]);
                o.f[2] = __float2half(acc[mf][nf][2]);
                o.f[3] = __float2half(acc[mf][nf][3]);
                *(ushort4*)(hp + (nf << 4)) = o.u;
            }
        }
    }
}

// ---------------------------------------------------------------------------
// Kernel 2 (coarse scatter, deterministic slots): each (sbin, block) owns a
// fixed SEG-record segment of cbuf -- NO global atomics (round-6's 12.5K
// cross-XCD cursor RMWs over 13 cache lines are gone). LDS-private cursors;
// per-segment counts written plainly to ccnt. Single pass over rows/cols/
// vals. Spill (+7 sigma) -> ovfbuf (LDS-counted, one per-block flush).
// Blocks >= SCAT_BLOCKS transform W fp32 -> f16 frag layout (precedes gemm).
// Record: { row<<16 | col , val_bits } (both < 65536).
// ---------------------------------------------------------------------------
__global__ __launch_bounds__(512) void scatter_coarse(const int* __restrict__ rows,
                                                      const int* __restrict__ cols,
                                                      const float* __restrict__ vals,
                                                      int* __restrict__ ccnt,
                                                      int* __restrict__ ovfcnt,
                                                      int2* __restrict__ cbuf,
                                                      int2* __restrict__ ovfbuf,
                                                      const float* __restrict__ w,
                                                      __half* __restrict__ wtl) {
    if (blockIdx.x >= SCAT_BLOCKS) {
        const int e0 = ((blockIdx.x - SCAT_BLOCKS) * 512 + threadIdx.x) * 8;
        const int k  = e0 >> 7;
        const int n0 = e0 & 127;
        const float4 a = *(const float4*)(w + e0);
        const float4 b = *(const float4*)(w + e0 + 4);
        __half* dst = wtl + ((size_t)((k >> 3) * 128 + n0)) * 8 + (k & 7);
        dst[0]  = __float2half(a.x);
        dst[8]  = __float2half(a.y);
        dst[16] = __float2half(a.z);
        dst[24] = __float2half(a.w);
        dst[32] = __float2half(b.x);
        dst[40] = __float2half(b.y);
        dst[48] = __float2half(b.z);
        dst[56] = __float2half(b.w);
        return;
    }

    __shared__ int lcur[NSB];
    const int t = threadIdx.x;
    const int blk = blockIdx.x;
    const int ebase = blk * EPB_S;

    if (t < NSB) lcur[t] = 0;
    __syncthreads();

#pragma unroll
    for (int k = 0; k < SCAT_ITERS; ++k) {
        const int i = k * 512 + t;
        if (i < EPB_S) {
            const int e = ebase + i;
            const int r = rows[e];
            const int sb = r >> SB_SH;
            const int off = atomicAdd(&lcur[sb], 1);     // LDS-private, no XCD traffic
            const int key = (int)(((unsigned)r << 16) | (unsigned)cols[e]);
            const int vb  = __float_as_int(vals[e]);
            if (off < SEG) {
                cbuf[((size_t)sb * SCAT_BLOCKS + blk) * SEG + off] = make_int2(key, vb);
            } else {
                const int p = atomicAdd(ovfcnt, 1);      // statistically unreachable
                if (p < OVF_CAP) ovfbuf[p] = make_int2(key, vb);
            }
        }
    }
    __syncthreads();

    if (t < NSB) ccnt[t * SCAT_BLOCKS + blk] = min(lcur[t], SEG);
}

// ---------------------------------------------------------------------------
// Kernel 3 (fine scatter, deterministic slots): block (sbin, part) streams
// the 32 source segments of its part (L2-hot, counts from ccnt) and writes
// each record into its fine bin's fixed (fbin, part) segment. LDS cursors
// only; counts -> fcnt. Each wave owns 4 source segments.
// Fine record: { col | (row & 31) << 16 , val_bits }.
// ---------------------------------------------------------------------------
__global__ __launch_bounds__(512) void scatter_fine(const int* __restrict__ ccnt,
                                                    int* __restrict__ fcnt,
                                                    int* __restrict__ ovfcnt,
                                                    const int2* __restrict__ cbuf,
                                                    int2* __restrict__ ebuf,
                                                    int2* __restrict__ ovfbuf) {
    __shared__ int lcur[32];
    __shared__ int scnt[32];
    const int t    = threadIdx.x;
    const int sb   = blockIdx.x / NPART;
    const int p    = blockIdx.x % NPART;
    const int wv   = t >> 6;
    const int lane = t & 63;

    if (t < 32) {
        lcur[t] = 0;
        scnt[t] = ccnt[sb * SCAT_BLOCKS + p * 32 + t];
    }
    __syncthreads();

    // wave wv handles source segments wv*4 .. wv*4+3
    for (int j = 0; j < 4; ++j) {
        const int seg = (wv << 2) + j;
        const int cnt = scnt[seg];
        const size_t sbase = ((size_t)sb * SCAT_BLOCKS + p * 32 + seg) * SEG;
        for (int i = lane; i < cnt; i += 64) {
            const int2 rc = cbuf[sbase + i];
            const unsigned urow = ((unsigned)rc.x) >> 16;
            const int fb = (int)((urow >> BIN_SH) & 31);
            const int off = atomicAdd(&lcur[fb], 1);
            const int key = (rc.x & 0xFFFF) | (int)((urow & (BIN_ROWS - 1)) << 16);
            if (off < SEG) {
                ebuf[(((size_t)sb * 32 + fb) * NPART + p) * SEG + off] = make_int2(key, rc.y);
            } else {
                const int q = atomicAdd(ovfcnt, 1);      // statistically unreachable
                if (q < OVF_CAP) ovfbuf[q] = rc;         // full-row format
            }
        }
    }
    __syncthreads();

    if (t < 32) fcnt[((sb * 32 + t) * NPART) + p] = min(lcur[t], SEG);
}

// ---------------------------------------------------------------------------
// Kernel 4 (FUSED sort+gather): one block per 32-row bin, 512 threads.
// Reads the bin's 8 part-counts (plain loads), flattens via a 9-entry
// prefix, 2-pass counting sort by (row,octant) class from L2-hot ebuf into
// ~13.3 KB LDS, then the depth-2-pipelined register gather (wave owns 4
// rows, 8 h-loads in flight). LDS ~15.6 KB -> 4 blocks/CU wave-capped
// (occupancy ~50%, vs round-6's 33%).
// ---------------------------------------------------------------------------
#define NCLS 256

#define STAGE(IT, HV, VV) do {                                                  \
    _Pragma("unroll")                                                           \
    for (int q = 0; q < 4; ++q) {                                               \
        const int idx = beg[q] + ((IT) << 2) + grp;                             \
        const bool vld = idx < end[q];                                          \
        const int2 r = srec[vld ? idx : 0];                                     \
        VV[q] = vld ? __int_as_float(r.y) : 0.f;                                \
        HV[q] = *(const f16x8*)(h + (size_t)(r.x & 0xFFFF) * OUT_DIM + (gl << 3)); \
    }                                                                           \
} while (0)

__global__ __launch_bounds__(512, 4) void sort_gather(const int* __restrict__ fcnt,
                                                      const int* __restrict__ ovfcnt,
                                                      const int2* __restrict__ ebuf,
                                                      const int2* __restrict__ ovfbuf,
                                                      const __half* __restrict__ h,
                                                      float* __restrict__ out) {
    __shared__ int2 srec[CAPB_TOT];        // 13.3 KB sorted records
    __shared__ int  hist[NCLS];
    __shared__ int  pfx[NCLS];
    __shared__ int  rowoff_l[BIN_ROWS + 1];
    __shared__ int  wsum[4];
    __shared__ int  poff[NPART + 1];

    const int t    = threadIdx.x;
    const int bin  = blockIdx.x;
    const int wv   = t >> 6;
    const int lane = t & 63;

    if (t < NCLS) hist[t] = 0;
    if (t == 0) {
        int a = 0;
        poff[0] = 0;
#pragma unroll
        for (int p = 0; p < NPART; ++p) { a += fcnt[bin * NPART + p]; poff[p + 1] = a; }
    }
    __syncthreads();
    const int cnt = poff[NPART];

    // flat index f -> (part, local i): part via 7 branchless compares
#define LOCATE(F, PP, II) do {                                                  \
        PP = 0;                                                                 \
        _Pragma("unroll")                                                       \
        for (int j = 1; j < NPART; ++j) PP += ((F) >= poff[j]);                 \
        II = (F) - poff[PP];                                                    \
    } while (0)

    // ---- pass 1: per-(row,octant) histogram ----
    for (int f = t; f < cnt; f += 512) {
        int p, i; LOCATE(f, p, i);
        const int k = ebuf[((size_t)bin * NPART + p) * SEG + i].x;
        atomicAdd(&hist[(((k >> 16) & 31) << 3) | ((k & 0xFFFF) >> 13)], 1);
    }
    __syncthreads();

    // ---- 256-class scan: 4-wave shfl scan + tiny combine ----
    {
        const int v = (t < NCLS) ? hist[t] : 0;
        int s = v;
#pragma unroll
        for (int off = 1; off < 64; off <<= 1) {
            const int u = __shfl_up(s, off);
            if (lane >= off) s += u;
        }
        if (t < NCLS && lane == 63) wsum[wv] = s;
        __syncthreads();
        if (t == 0) {
            int a = 0;
#pragma unroll
            for (int i = 0; i < 4; ++i) { const int c = wsum[i]; wsum[i] = a; a += c; }
        }
        __syncthreads();
        if (t < NCLS) {
            const int incl = s + wsum[wv];
            pfx[t]  = incl;
            hist[t] = incl - v;
        }
    }
    __syncthreads();
    if (t < BIN_ROWS) rowoff_l[t] = t ? pfx[(t << 3) - 1] : 0;
    if (t == BIN_ROWS) rowoff_l[BIN_ROWS] = cnt;
    __syncthreads();

    // ---- pass 2: counting sort (re-read L2-hot ebuf) ----
    for (int f = t; f < cnt; f += 512) {
        int p, i; LOCATE(f, p, i);
        const int2 r = ebuf[((size_t)bin * NPART + p) * SEG + i];
        const int cls = (((r.x >> 16) & 31) << 3) | ((r.x & 0xFFFF) >> 13);
        const int pos = atomicAdd(&hist[cls], 1);
        srec[pos] = r;
    }
    __syncthreads();

    // ---- gather: wave owns 4 rows, depth-2 pipeline ----
    const int grp = lane >> 4;
    const int gl  = lane & 15;
    const int r0  = wv << 2;

    int beg[4], end[4];
#pragma unroll
    for (int q = 0; q < 4; ++q) { beg[q] = rowoff_l[r0 + q]; end[q] = rowoff_l[r0 + q + 1]; }
    int nmax = 0;
#pragma unroll
    for (int q = 0; q < 4; ++q) nmax = max(nmax, end[q] - beg[q]);
    const int iters = (nmax + 3) >> 2;

    f32x8 acc[4];
#pragma unroll
    for (int q = 0; q < 4; ++q) acc[q] = (f32x8){0.f,0.f,0.f,0.f,0.f,0.f,0.f,0.f};

    f16x8 hc[4], hn[4];
    float vc[4], vn[4];
    if (iters > 0) STAGE(0, hc, vc);
    for (int it = 0; it < iters; ++it) {
        if (it + 1 < iters) STAGE(it + 1, hn, vn);
#pragma unroll
        for (int q = 0; q < 4; ++q)
#pragma unroll
            for (int j = 0; j < 8; ++j) acc[q][j] += vc[q] * (float)hc[q][j];
#pragma unroll
        for (int q = 0; q < 4; ++q) { hc[q] = hn[q]; vc[q] = vn[q]; }
    }

    // ---- overflow replay (0 in practice) ----
    int novf = *ovfcnt;
    if (novf > OVF_CAP) novf = OVF_CAP;
    for (int e = 0; e < novf; ++e) {
        const int2 rec = ovfbuf[e];
        const unsigned urow = ((unsigned)rec.x) >> 16;
        if ((int)(urow >> BIN_SH) == bin && grp == 0) {
            const int lr = (int)(urow & (BIN_ROWS - 1)) - r0;
            if (lr >= 0 && lr < 4) {
                const float v = __int_as_float(rec.y);
                const f16x8 hv = *(const f16x8*)(h + (size_t)(rec.x & 0xFFFF) * OUT_DIM + (gl << 3));
#pragma unroll
                for (int q = 0; q < 4; ++q)
                    if (q == lr)
#pragma unroll
                        for (int j = 0; j < 8; ++j) acc[q][j] += v * (float)hv[j];
            }
        }
    }

    // ---- reduce across the 4 edge-slot groups ----
#pragma unroll
    for (int q = 0; q < 4; ++q)
#pragma unroll
        for (int j = 0; j < 8; ++j) {
            float x = acc[q][j];
            x += __shfl_xor(x, 16);
            x += __shfl_xor(x, 32);
            acc[q][j] = x;
        }

    float res[8];
#pragma unroll
    for (int j = 0; j < 8; ++j) {
        float x = acc[0][j];
        x = (grp == 1) ? acc[1][j] : x;
        x = (grp == 2) ? acc[2][j] : x;
        x = (grp == 3) ? acc[3][j] : x;
        res[j] = lrelu(x);
    }
    const int grow = (bin << BIN_SH) + r0 + grp;
    if (grow < N_NODES) {
        float* op = out + (size_t)grow * OUT_DIM + (gl << 3);
        *(float4*)op       = make_float4(res[0], res[1], res[2], res[3]);
        *(float4*)(op + 4) = make_float4(res[4], res[5], res[6], res[7]);
    }
}

// ---------------------------------------------------------------------------
// Launch: memset(4B) -> coarse(+convW) -> fine -> gemm -> sort_gather.
// cbuf dead after fine, so h ALIASES it. No global atomics anywhere on the
// hot path; ccnt/fcnt fully overwritten each run (no zeroing needed).
// ---------------------------------------------------------------------------
extern "C" void kernel_launch(void* const* d_in, const int* in_sizes, int n_in,
                              void* d_out, int out_size, void* d_ws, size_t ws_size,
                              hipStream_t stream) {
    const float* x    = (const float*)d_in[0];
    const float* w    = (const float*)d_in[1];
    const float* vals = (const float*)d_in[2];
    const int*   rows = (const int*)d_in[3];
    const int*   cols = (const int*)d_in[4];
    float* out = (float*)d_out;

    char* ws = (char*)d_ws;
    size_t off = 0;
    auto alloc = [&](size_t bytes) {
        void* p = ws + off;
        off = (off + bytes + 255) & ~(size_t)255;
        return p;
    };
    int2*  cbuf    = (int2*) alloc((size_t)NSB * SCAT_BLOCKS * SEG * sizeof(int2)); // 20.9 MB
    __half* h      = (__half*)cbuf;   // alias: h (12.8 MB) reuses dead cbuf
    int2*  ebuf    = (int2*) alloc((size_t)NBIN_PAD * NPART * SEG * sizeof(int2));  // 20.9 MB
    int2*  ovfbuf  = (int2*) alloc((size_t)OVF_CAP * sizeof(int2));                 // 0.5 MB
    __half* wtl    = (__half*)alloc((size_t)IN_DIM * OUT_DIM * sizeof(__half));     // 64 KB
    int*   ccnt    = (int*)  alloc((size_t)NSB * SCAT_BLOCKS * sizeof(int));        // 50 KB
    int*   fcnt    = (int*)  alloc((size_t)NBIN_PAD * NPART * sizeof(int));         // 50 KB
    int*   ovfcnt  = (int*)  alloc(sizeof(int));

    hipMemsetAsync(ovfcnt, 0, sizeof(int), stream);

    scatter_coarse<<<SCAT_BLOCKS + CONVW_BLOCKS, 512, 0, stream>>>(rows, cols, vals,
                                                                   ccnt, ovfcnt, cbuf, ovfbuf, w, wtl);
    scatter_fine<<<NSB * NPART, 512, 0, stream>>>(ccnt, fcnt, ovfcnt, cbuf, ebuf, ovfbuf);
    gemm_xw_mfma<<<GEMM_BLOCKS, 256, 0, stream>>>(x, wtl, h);
    sort_gather<<<NBIN, 512, 0, stream>>>(fcnt, ovfcnt, ebuf, ovfbuf, h, out);
}